// Round 7
// baseline (334.142 us; speedup 1.0000x reference)
//
#include <hip/hip_runtime.h>
#include <hip/hip_bf16.h>

#define NTOK 49
#define DIM 256
#define HEADS 8
#define HD 32
#define SCALE 0.17677669529663687f

typedef float f32x4 __attribute__((ext_vector_type(4)));
typedef short bf16x8 __attribute__((ext_vector_type(8)));

__device__ __forceinline__ unsigned short f2bf(float f) {
    union { __hip_bfloat16 h; unsigned short u; } c;
    c.h = __float2bfloat16(f);
    return c.u;
}
__device__ __forceinline__ float bf2f(unsigned short u) {
    return __builtin_bit_cast(float, (unsigned)u << 16);
}

// 16-lane-row rotate (DPP row_ror:N); softmax reductions over l15.
template<int CTRL>
__device__ __forceinline__ float dpp_rot(float x) {
    int i = __builtin_bit_cast(int, x);
    int r = __builtin_amdgcn_update_dpp(i, i, CTRL, 0xF, 0xF, true);
    return __builtin_bit_cast(float, r);
}

// ---------------------------------------------------------------------------
// K0: one-time prep into d_ws (unchanged):
//   wqf [196608] bf16 : qkv_w in MFMA B-fragment order
//   wpf [65536]  bf16 : proj_w in MFMA B-fragment order
//   bmf [2097152] bf16 : mask+bias in softmax D-fragment order
// ---------------------------------------------------------------------------
__global__ void k0_prep(const float* __restrict__ qkv_w, const float* __restrict__ proj_w,
                        const float* __restrict__ mask, const float* __restrict__ bias_table,
                        const int* __restrict__ rel_idx,
                        unsigned short* __restrict__ wqf, unsigned short* __restrict__ wpf,
                        unsigned short* __restrict__ bmf, int total)
{
    int i = blockIdx.x * 256 + threadIdx.x;
    if (i >= total) return;
    if (i < 196608) {
        int j = i & 7, q = i >> 3;
        int lane = q & 63; q >>= 6;
        int ks2 = q & 7;  q >>= 3;
        int tt = q % 6;   q /= 6;
        int h  = q;
        int n96 = tt * 16 + (lane & 15);
        int seg = n96 >> 5, ch = n96 & 31;
        wqf[i] = f2bf(qkv_w[(seg * 256 + h * HD + ch) * 256 + ks2 * 32 + (lane >> 4) * 8 + j]);
    } else if (i < 262144) {
        int u = i - 196608;
        int j = u & 7, q = u >> 3;
        int lane = q & 63; q >>= 6;
        int ks2 = q & 7;  q >>= 3;
        int bt = q;                       // 0..15
        int n = (bt >> 3) * 128 + (bt & 7) * 16 + (lane & 15);
        wpf[u] = f2bf(proj_w[n * 256 + ks2 * 32 + (lane >> 4) * 8 + j]);
    } else {
        int u = i - 262144;               // [0, 2097152)
        int nt = u & 3;
        int lane = (u >> 2) & 63;
        int g = u >> 8;                   // wslot*128 + h*16 + mt*4 + jj
        int jj = g & 3, mt = (g >> 2) & 3, h = (g >> 4) & 7, ws = g >> 7;
        int r = mt * 16 + (lane >> 4) * 4 + jj;
        int c = nt * 16 + (lane & 15);
        float v = 0.f;
        if (r < NTOK && c < NTOK)
            v = mask[ws * 2401 + r * NTOK + c] + bias_table[rel_idx[r * NTOK + c] * HEADS + h];
        bmf[u] = f2bf(v);
    }
}

// ---------------------------------------------------------------------------
// K1: fully fused qkv + attention + proj. 4096 blocks x 256 threads (4 waves).
// Wave wv owns heads {wv, wv+4}; wave-private LDS; 3 barriers per block.
// __launch_bounds__(256, 2): min 2 waves/EU -> VGPR budget 256 (LDS caps
// occupancy at 2 blocks/CU anyway). Round-6's attribute form was ignored
// (VGPR stayed 128, ~23 f32/thread scratch traffic); this is the documented
// HIP spelling.
// LDS pool:
//   xs  [49][256] bf16 swizzled     sh [0,12544)   (x; reused for ao)
//   per wave wv at base W = 12544 + wv*6464:
//     qw  [52][40] bf16             W+0    (2080)
//     kw  [52][40] bf16             W+2080 (2080)
//     vtw [32][72] bf16 (v^T)       W+4160 (2304)
//     pw_ [52][64] bf16 swizzled    W+0    (aliases qw/kw; q/k frags are read
//                                    into registers before P is written)
// ---------------------------------------------------------------------------
__global__ __launch_bounds__(256, 2)
void k1_fused(
    const float* __restrict__ x,             // [4096,49,256] f32
    const float* __restrict__ qkv_b,         // [768] f32
    const float* __restrict__ pb,            // [256] f32
    const unsigned short* __restrict__ wqf,  // fragment-ordered qkv_w bf16
    const unsigned short* __restrict__ wpf,  // fragment-ordered proj_w bf16
    const unsigned short* __restrict__ bmf,  // fragment-ordered mask+bias bf16
    float* __restrict__ out)                 // [4096,49,256] f32 final
{
    __shared__ unsigned short pool[38400];
    unsigned short* const xs = pool;

    const int t = threadIdx.x, bw = blockIdx.x;
    const int lane = t & 63, wv = t >> 6;
    const int l15 = lane & 15, l16 = lane >> 4;
    unsigned short* const qw  = pool + 12544 + wv * 6464;
    unsigned short* const kw  = qw + 2080;
    unsigned short* const vtw = qw + 4160;
    unsigned short* const pw_ = qw;

    // ---- stage x rows 0..48 -> bf16 LDS (XOR swizzle on 16B chunks)
    const float* xw = x + (size_t)bw * NTOK * DIM;
    for (int cidx = t; cidx < NTOK * 32; cidx += 256) {
        int row = cidx >> 5, c8 = cidx & 31;
        float4 a = *(const float4*)(xw + row * DIM + c8 * 8);
        float4 b = *(const float4*)(xw + row * DIM + c8 * 8 + 4);
        bf16x8 v;
        v[0] = (short)f2bf(a.x); v[1] = (short)f2bf(a.y);
        v[2] = (short)f2bf(a.z); v[3] = (short)f2bf(a.w);
        v[4] = (short)f2bf(b.x); v[5] = (short)f2bf(b.y);
        v[6] = (short)f2bf(b.z); v[7] = (short)f2bf(b.w);
        *(bf16x8*)(xs + row * 256 + ((c8 * 8) ^ ((row & 7) << 3))) = v;
    }
    __syncthreads();   // barrier 1: xs ready

    int arow[4], rq[4];
    #pragma unroll
    for (int mt = 0; mt < 4; ++mt) {
        int r = mt * 16 + l15;
        arow[mt] = r > 48 ? 48 : r;     // xs / pw_ reads (49 real rows)
        rq[mt]   = r > 51 ? 51 : r;     // qw / kw reads (52 rows)
    }
    const int wimg = (bw & 63) << 7;

    unsigned int ob[2][4][2][2];        // packed bf16 PV outputs (2 heads)

    #pragma unroll
    for (int hh = 0; hh < 2; ++hh) {
        const int h = wv + 4 * hh;
        const unsigned short* wb = wqf + (size_t)h * 24576;
        ushort4 bmu[4][4];

        // ---------- qkv GEMM: 4 M-tiles x 6 N-tiles, two register passes ----
        #pragma unroll
        for (int p = 0; p < 2; ++p) {
            f32x4 acc[4][3];
            #pragma unroll
            for (int mt = 0; mt < 4; ++mt)
                #pragma unroll
                for (int tt = 0; tt < 3; ++tt) acc[mt][tt] = (f32x4){0.f,0.f,0.f,0.f};

            __builtin_amdgcn_s_setprio(1);
            #pragma unroll
            for (int ks2 = 0; ks2 < 8; ++ks2) {
                bf16x8 a[4], b[3];
                #pragma unroll
                for (int mt = 0; mt < 4; ++mt)
                    a[mt] = *(const bf16x8*)(xs + arow[mt] * 256 +
                              ((ks2 * 32 + l16 * 8) ^ ((arow[mt] & 7) << 3)));
                #pragma unroll
                for (int tt = 0; tt < 3; ++tt)
                    b[tt] = *(const bf16x8*)(wb + ((p * 3 + tt) * 8 + ks2) * 512 + lane * 8);
                #pragma unroll
                for (int mt = 0; mt < 4; ++mt)
                    #pragma unroll
                    for (int tt = 0; tt < 3; ++tt)
                        acc[mt][tt] = __builtin_amdgcn_mfma_f32_16x16x32_bf16(
                            a[mt], b[tt], acc[mt][tt], 0, 0, 0);
            }
            __builtin_amdgcn_s_setprio(0);

            if (p == 0) {   // prefetch softmax bias+mask frags (hide under pass 1)
                #pragma unroll
                for (int mt = 0; mt < 4; ++mt)
                    #pragma unroll
                    for (int jj = 0; jj < 4; ++jj)
                        bmu[mt][jj] = *(const ushort4*)(bmf +
                            (((size_t)(wimg + h * 16 + mt * 4 + jj)) << 8) + (lane << 2));
            }

            // epilogue: q (scaled) / k row-major; v transposed
            #pragma unroll
            for (int tt = 0; tt < 3; ++tt) {
                int n96 = (p * 3 + tt) * 16 + l15;
                int seg = n96 >> 5, ch = n96 & 31;
                float bias = qkv_b[seg * 256 + h * HD + ch];
                #pragma unroll
                for (int mt = 0; mt < 4; ++mt) {
                    int r0 = mt * 16 + l16 * 4;
                    if (seg == 2) {
                        unsigned int lo = (unsigned)f2bf(acc[mt][tt][0] + bias) |
                                          ((unsigned)f2bf(acc[mt][tt][1] + bias) << 16);
                        unsigned int hi = (unsigned)f2bf(acc[mt][tt][2] + bias) |
                                          ((unsigned)f2bf(acc[mt][tt][3] + bias) << 16);
                        *(uint2*)(vtw + ch * 72 + r0) = make_uint2(lo, hi);
                    } else if (seg == 0) {
                        #pragma unroll
                        for (int j = 0; j < 4; ++j)
                            if (r0 + j < 52)
                                qw[(r0 + j) * 40 + ch] = f2bf((acc[mt][tt][j] + bias) * SCALE);
                    } else {
                        #pragma unroll
                        for (int j = 0; j < 4; ++j)
                            if (r0 + j < 52)
                                kw[(r0 + j) * 40 + ch] = f2bf(acc[mt][tt][j] + bias);
                    }
                }
            }
        }

        // ---------- read ALL q/k fragments into registers (qw/kw then dead) -
        bf16x8 aq[4], bk[4];
        #pragma unroll
        for (int mt = 0; mt < 4; ++mt)
            aq[mt] = *(const bf16x8*)(qw + rq[mt] * 40 + l16 * 8);
        #pragma unroll
        for (int nt = 0; nt < 4; ++nt)
            bk[nt] = *(const bf16x8*)(kw + rq[nt] * 40 + l16 * 8);

        // ---------- S + softmax + P-store, split in two mt-halves ----------
        #pragma unroll
        for (int half = 0; half < 2; ++half) {
            f32x4 s[2][4];
            __builtin_amdgcn_s_setprio(1);
            #pragma unroll
            for (int m2 = 0; m2 < 2; ++m2)
                #pragma unroll
                for (int nt = 0; nt < 4; ++nt) {
                    f32x4 z = (f32x4){0.f,0.f,0.f,0.f};
                    s[m2][nt] = __builtin_amdgcn_mfma_f32_16x16x32_bf16(
                        aq[half * 2 + m2], bk[nt], z, 0, 0, 0);
                }
            __builtin_amdgcn_s_setprio(0);

            #pragma unroll
            for (int m2 = 0; m2 < 2; ++m2) {
                const int mt = half * 2 + m2;
                #pragma unroll
                for (int j = 0; j < 4; ++j) {
                    int r = mt * 16 + l16 * 4 + j;
                    float bmv[4] = { bf2f(bmu[mt][j].x), bf2f(bmu[mt][j].y),
                                     bf2f(bmu[mt][j].z), bf2f(bmu[mt][j].w) };
                    float vv[4];
                    float mx = -1e30f;
                    #pragma unroll
                    for (int nt = 0; nt < 4; ++nt) {
                        int c = nt * 16 + l15;
                        float v = s[m2][nt][j] + bmv[nt];
                        if (c >= NTOK) v = -1e30f;
                        vv[nt] = v;
                        mx = fmaxf(mx, v);
                    }
                    mx = fmaxf(mx, dpp_rot<0x121>(mx));
                    mx = fmaxf(mx, dpp_rot<0x122>(mx));
                    mx = fmaxf(mx, dpp_rot<0x124>(mx));
                    mx = fmaxf(mx, dpp_rot<0x128>(mx));
                    float sum = 0.f;
                    #pragma unroll
                    for (int nt = 0; nt < 4; ++nt) {
                        float e = __expf(vv[nt] - mx);
                        vv[nt] = e;
                        sum += e;
                    }
                    sum += dpp_rot<0x121>(sum);
                    sum += dpp_rot<0x122>(sum);
                    sum += dpp_rot<0x124>(sum);
                    sum += dpp_rot<0x128>(sum);
                    float inv = 1.f / sum;
                    if (r < 52) {
                        #pragma unroll
                        for (int nt = 0; nt < 4; ++nt) {
                            int c = nt * 16 + l15;
                            pw_[r * 64 + (c ^ ((r & 7) << 3))] = f2bf(vv[nt] * inv);
                        }
                    }
                }
            }
        }

        // ---------- out_h = P @ v : 4 M-tiles x 2 N-tiles, K=64 ----------
        f32x4 o[4][2];
        #pragma unroll
        for (int mt = 0; mt < 4; ++mt)
            #pragma unroll
            for (int nt = 0; nt < 2; ++nt) o[mt][nt] = (f32x4){0.f,0.f,0.f,0.f};
        __builtin_amdgcn_s_setprio(1);
        #pragma unroll
        for (int kt = 0; kt < 2; ++kt) {
            bf16x8 ap[4];
            #pragma unroll
            for (int mt = 0; mt < 4; ++mt)
                ap[mt] = *(const bf16x8*)(pw_ + arow[mt] * 64 +
                           ((kt * 32 + l16 * 8) ^ ((arow[mt] & 7) << 3)));
            #pragma unroll
            for (int nt = 0; nt < 2; ++nt) {
                bf16x8 bv = *(const bf16x8*)(vtw + (nt * 16 + l15) * 72 + kt * 32 + l16 * 8);
                #pragma unroll
                for (int mt = 0; mt < 4; ++mt)
                    o[mt][nt] = __builtin_amdgcn_mfma_f32_16x16x32_bf16(
                        ap[mt], bv, o[mt][nt], 0, 0, 0);
            }
        }
        __builtin_amdgcn_s_setprio(0);

        // pack to bf16 immediately (identical numerics to the later scatter)
        #pragma unroll
        for (int mt = 0; mt < 4; ++mt)
            #pragma unroll
            for (int nt = 0; nt < 2; ++nt)
                #pragma unroll
                for (int pr = 0; pr < 2; ++pr)
                    ob[hh][mt][nt][pr] =
                        (unsigned)f2bf(o[mt][nt][pr * 2]) |
                        ((unsigned)f2bf(o[mt][nt][pr * 2 + 1]) << 16);
    }

    __syncthreads();   // barrier 2: all waves past their last xs read

    // ---- scatter attention output (both heads) into xs as bf16, swizzled
    #pragma unroll
    for (int hh = 0; hh < 2; ++hh) {
        #pragma unroll
        for (int mt = 0; mt < 4; ++mt) {
            #pragma unroll
            for (int nt = 0; nt < 2; ++nt) {
                #pragma unroll
                for (int j = 0; j < 4; ++j) {
                    int tok = mt * 16 + l16 * 4 + j;
                    if (tok < NTOK) {
                        int ch = (wv + 4 * hh) * HD + nt * 16 + l15;
                        int ad = tok * 256 + ((ch & ~7) ^ ((tok & 7) << 3)) + (ch & 7);
                        xs[ad] = (unsigned short)(ob[hh][mt][nt][j >> 1] >> (16 * (j & 1)));
                    }
                }
            }
        }
    }
    __syncthreads();   // barrier 3: ao ready in xs

    // ---- proj: out = ao @ proj_w^T + pb. Wave covers 4 col-tiles (64 cols).
    f32x4 pacc[4][4];
    #pragma unroll
    for (int mt = 0; mt < 4; ++mt)
        #pragma unroll
        for (int u = 0; u < 4; ++u) pacc[mt][u] = (f32x4){0.f,0.f,0.f,0.f};

    int pcol[4];
    float pbv[4];
    #pragma unroll
    for (int u = 0; u < 4; ++u) {
        int bt = wv * 4 + u;
        pcol[u] = (bt >> 3) * 128 + (bt & 7) * 16 + l15;
        pbv[u] = pb[pcol[u]];
    }

    __builtin_amdgcn_s_setprio(1);
    #pragma unroll
    for (int ks2 = 0; ks2 < 8; ++ks2) {
        bf16x8 a[4];
        #pragma unroll
        for (int mt = 0; mt < 4; ++mt)
            a[mt] = *(const bf16x8*)(xs + arow[mt] * 256 +
                      ((ks2 * 32 + l16 * 8) ^ ((arow[mt] & 7) << 3)));
        #pragma unroll
        for (int u = 0; u < 4; ++u) {
            bf16x8 b = *(const bf16x8*)(wpf + (size_t)((wv * 4 + u) * 8 + ks2) * 512 + lane * 8);
            #pragma unroll
            for (int mt = 0; mt < 4; ++mt)
                pacc[mt][u] = __builtin_amdgcn_mfma_f32_16x16x32_bf16(
                    a[mt], b, pacc[mt][u], 0, 0, 0);
        }
    }
    __builtin_amdgcn_s_setprio(0);

    #pragma unroll
    for (int u = 0; u < 4; ++u) {
        #pragma unroll
        for (int mt = 0; mt < 4; ++mt) {
            #pragma unroll
            for (int j = 0; j < 4; ++j) {
                int tok = mt * 16 + l16 * 4 + j;
                if (tok < NTOK)
                    out[((size_t)bw * NTOK + tok) * DIM + pcol[u]] = pacc[mt][u][j] + pbv[u];
            }
        }
    }
}

extern "C" void kernel_launch(void* const* d_in, const int* in_sizes, int n_in,
                              void* d_out, int out_size, void* d_ws, size_t ws_size,
                              hipStream_t stream) {
    const float* x    = (const float*)d_in[0];
    const float* mask = (const float*)d_in[1];
    const float* qkvw = (const float*)d_in[2];
    const float* qkvb = (const float*)d_in[3];
    const float* pw   = (const float*)d_in[4];
    const float* pb   = (const float*)d_in[5];
    const float* bt   = (const float*)d_in[6];
    const int*   ri   = (const int*)d_in[7];
    float* out = (float*)d_out;

    unsigned short* wqf = (unsigned short*)d_ws;
    unsigned short* wpf = wqf + 196608;
    unsigned short* bmf = (unsigned short*)((char*)d_ws + 524288);  // 4 MB

    const int nwin = in_sizes[0] / (NTOK * DIM);      // 4096
    const int total = 262144 + 64 * HEADS * 16 * 256; // 2359296

    k0_prep<<<(total + 255) / 256, 256, 0, stream>>>(qkvw, pw, mask, bt, ri,
                                                     wqf, wpf, bmf, total);
    k1_fused<<<nwin, 256, 0, stream>>>(x, qkvb, pb, wqf, wpf, bmf, out);
}

// Round 8
// 268.510 us; speedup vs baseline: 1.2444x; 1.2444x over previous
//
#include <hip/hip_runtime.h>
#include <hip/hip_bf16.h>

#define NTOK 49
#define DIM 256
#define HEADS 8
#define HD 32
#define SCALE 0.17677669529663687f

typedef float f32x4 __attribute__((ext_vector_type(4)));
typedef short bf16x8 __attribute__((ext_vector_type(8)));

__device__ __forceinline__ unsigned short f2bf(float f) {
    union { __hip_bfloat16 h; unsigned short u; } c;
    c.h = __float2bfloat16(f);
    return c.u;
}
__device__ __forceinline__ float bf2f(unsigned short u) {
    return __builtin_bit_cast(float, (unsigned)u << 16);
}
__device__ __forceinline__ uint2 pack4(float a, float b, float c, float d) {
    uint2 r;
    r.x = (unsigned)f2bf(a) | ((unsigned)f2bf(b) << 16);
    r.y = (unsigned)f2bf(c) | ((unsigned)f2bf(d) << 16);
    return r;
}

// ---------------------------------------------------------------------------
// K0: one-time prep into d_ws:
//   wqf [196608] bf16 : qkv_w in MFMA fragment order (UNCHANGED layout)
//   wpf [65536]  bf16 : proj_w in MFMA fragment order (UNCHANGED layout)
//   bmf [2097152] bf16 : mask+bias in S^T D-fragment order (NEW):
//       idx = ((ws*8+h)*16 + ct*4 + mt)*256 + lane*4 + j
//       -> value at (query q = ct*16 + (lane&15), key = mt*16 + (lane>>4)*4 + j)
// ---------------------------------------------------------------------------
__global__ void k0_prep(const float* __restrict__ qkv_w, const float* __restrict__ proj_w,
                        const float* __restrict__ mask, const float* __restrict__ bias_table,
                        const int* __restrict__ rel_idx,
                        unsigned short* __restrict__ wqf, unsigned short* __restrict__ wpf,
                        unsigned short* __restrict__ bmf, int total)
{
    int i = blockIdx.x * 256 + threadIdx.x;
    if (i >= total) return;
    if (i < 196608) {
        int j = i & 7, q = i >> 3;
        int lane = q & 63; q >>= 6;
        int ks2 = q & 7;  q >>= 3;
        int tt = q % 6;   q /= 6;
        int h  = q;
        int n96 = tt * 16 + (lane & 15);
        int seg = n96 >> 5, ch = n96 & 31;
        wqf[i] = f2bf(qkv_w[(seg * 256 + h * HD + ch) * 256 + ks2 * 32 + (lane >> 4) * 8 + j]);
    } else if (i < 262144) {
        int u = i - 196608;
        int j = u & 7, q = u >> 3;
        int lane = q & 63; q >>= 6;
        int ks2 = q & 7;  q >>= 3;
        int bt = q;                       // 0..15
        int n = (bt >> 3) * 128 + (bt & 7) * 16 + (lane & 15);
        wpf[u] = f2bf(proj_w[n * 256 + ks2 * 32 + (lane >> 4) * 8 + j]);
    } else {
        int u = i - 262144;               // [0, 2097152)
        int j = u & 3;
        int lane = (u >> 2) & 63;
        int g = u >> 8;                   // ws*128 + h*16 + ct*4 + mt
        int mt = g & 3, ct = (g >> 2) & 3, h = (g >> 4) & 7, ws = g >> 7;
        int q = ct * 16 + (lane & 15);
        int key = mt * 16 + ((lane >> 4) & 3) * 4 + j;
        float v = 0.f;
        if (q < NTOK && key < NTOK)
            v = mask[ws * 2401 + q * NTOK + key] + bias_table[rel_idx[q * NTOK + key] * HEADS + h];
        bmf[u] = f2bf(v);
    }
}

// ---------------------------------------------------------------------------
// K1: fully fused qkv + attention + proj. 4096 blocks x 256 threads (4 waves).
// Wave wv owns heads {wv, wv+4}; wave-private LDS; 3 barriers per block.
// All GEMMs operand-SWAPPED (except v) so D-fragments are store-friendly:
// every LDS store is a packed b64, the out store is a float4.
// D-mapping rule (verified r2..r7): D.col(l15) = operand-2's l15 label,
//                                   D.row(l16*4+j) = operand-1's l15 label.
// LDS pool 74880 B -> 2 blocks/CU:
//   xs  [49][256] bf16 swizzled     sh [0,12544)  (x; reused for ao)
//   per wave wv at base W = 12544 + wv*6224:
//     qw  [49][40] bf16 [tok][ch]   W+0    (1960)
//     kw  [49][40] bf16 [tok][ch]   W+1960 (1960)
//     vtw [32][72] bf16 [ch][tok]   W+3920 (2304)
//     pw2 [49][72] bf16 [q][key]    W+0    (3528, aliases qw/kw; q/k frags are
//                                    preloaded to regs before P is written)
// ---------------------------------------------------------------------------
__global__ __launch_bounds__(256, 2)
void k1_fused(
    const float* __restrict__ x,             // [4096,49,256] f32
    const float* __restrict__ qkv_b,         // [768] f32
    const float* __restrict__ pb,            // [256] f32
    const unsigned short* __restrict__ wqf,  // fragment-ordered qkv_w bf16
    const unsigned short* __restrict__ wpf,  // fragment-ordered proj_w bf16
    const unsigned short* __restrict__ bmf,  // fragment-ordered mask+bias bf16
    float* __restrict__ out)                 // [4096,49,256] f32 final
{
    __shared__ unsigned short pool[37440];
    unsigned short* const xs = pool;

    const int t = threadIdx.x, bw = blockIdx.x;
    const int lane = t & 63, wv = t >> 6;
    const int l15 = lane & 15, l16 = lane >> 4;
    unsigned short* const qw  = pool + 12544 + wv * 6224;
    unsigned short* const kw  = qw + 1960;
    unsigned short* const vtw = qw + 3920;
    unsigned short* const pw2 = qw;

    // ---- stage x rows 0..48 -> bf16 LDS (XOR swizzle on 16B chunks)
    const float* xw = x + (size_t)bw * NTOK * DIM;
    for (int cidx = t; cidx < NTOK * 32; cidx += 256) {
        int row = cidx >> 5, c8 = cidx & 31;
        float4 a = *(const float4*)(xw + row * DIM + c8 * 8);
        float4 b = *(const float4*)(xw + row * DIM + c8 * 8 + 4);
        bf16x8 v;
        v[0] = (short)f2bf(a.x); v[1] = (short)f2bf(a.y);
        v[2] = (short)f2bf(a.z); v[3] = (short)f2bf(a.w);
        v[4] = (short)f2bf(b.x); v[5] = (short)f2bf(b.y);
        v[6] = (short)f2bf(b.z); v[7] = (short)f2bf(b.w);
        *(bf16x8*)(xs + row * 256 + ((c8 * 8) ^ ((row & 7) << 3))) = v;
    }
    __syncthreads();   // barrier 1: xs ready

    int arow[4];
    #pragma unroll
    for (int i4 = 0; i4 < 4; ++i4) {
        int r = i4 * 16 + l15;
        arow[i4] = r > 48 ? 48 : r;     // row clamp for all 49-row buffers
    }

    uint2 ob[2][2][4];                  // packed bf16 out^T frags [hh][a][ct]

    #pragma unroll
    for (int hh = 0; hh < 2; ++hh) {
        const int h = wv + 4 * hh;
        const unsigned short* wb = wqf + (size_t)h * 24576;
        uint2 bmu[4][4];                // [ct][mt] bias+mask frags

        // ---------- qkv: 2 passes; q,k swapped (D: tok=l15, ch in regs) -----
        #pragma unroll
        for (int p = 0; p < 2; ++p) {
            f32x4 aq[4], ak[4], av[4];
            #pragma unroll
            for (int nt = 0; nt < 4; ++nt) {
                aq[nt] = (f32x4){0.f,0.f,0.f,0.f};
                ak[nt] = (f32x4){0.f,0.f,0.f,0.f};
                av[nt] = (f32x4){0.f,0.f,0.f,0.f};
            }
            __builtin_amdgcn_s_setprio(1);
            #pragma unroll
            for (int ks2 = 0; ks2 < 8; ++ks2) {
                bf16x8 xf[4];
                #pragma unroll
                for (int nt = 0; nt < 4; ++nt)
                    xf[nt] = *(const bf16x8*)(xs + arow[nt] * 256 +
                               ((ks2 * 32 + l16 * 8) ^ ((arow[nt] & 7) << 3)));
                bf16x8 wqf_ = *(const bf16x8*)(wb + ((p    ) * 8 + ks2) * 512 + lane * 8);
                bf16x8 wkf_ = *(const bf16x8*)(wb + ((2 + p) * 8 + ks2) * 512 + lane * 8);
                bf16x8 wvf_ = *(const bf16x8*)(wb + ((4 + p) * 8 + ks2) * 512 + lane * 8);
                #pragma unroll
                for (int nt = 0; nt < 4; ++nt) {
                    aq[nt] = __builtin_amdgcn_mfma_f32_16x16x32_bf16(wqf_, xf[nt], aq[nt], 0, 0, 0);
                    ak[nt] = __builtin_amdgcn_mfma_f32_16x16x32_bf16(wkf_, xf[nt], ak[nt], 0, 0, 0);
                    av[nt] = __builtin_amdgcn_mfma_f32_16x16x32_bf16(xf[nt], wvf_, av[nt], 0, 0, 0);
                }
            }
            __builtin_amdgcn_s_setprio(0);

            if (p == 0) {   // prefetch softmax bias+mask frags (hide under pass 1)
                #pragma unroll
                for (int ct = 0; ct < 4; ++ct)
                    #pragma unroll
                    for (int mt = 0; mt < 4; ++mt)
                        bmu[ct][mt] = *(const uint2*)(bmf +
                            (((size_t)(((bw & 63) * 8 + h) * 16 + ct * 4 + mt)) << 8) + (lane << 2));
            }

            // epilogue: q/k packed-row stores; v transposed (unchanged form)
            float4 bq4 = *(const float4*)(qkv_b + h * HD + p * 16 + l16 * 4);
            float4 bk4 = *(const float4*)(qkv_b + 256 + h * HD + p * 16 + l16 * 4);
            float  bvs = qkv_b[512 + h * HD + p * 16 + l15];
            #pragma unroll
            for (int nt = 0; nt < 4; ++nt) {
                int tok = nt * 16 + l15;
                if (tok < NTOK) {
                    *(uint2*)(qw + tok * 40 + p * 16 + l16 * 4) =
                        pack4((aq[nt][0] + bq4.x) * SCALE, (aq[nt][1] + bq4.y) * SCALE,
                              (aq[nt][2] + bq4.z) * SCALE, (aq[nt][3] + bq4.w) * SCALE);
                    *(uint2*)(kw + tok * 40 + p * 16 + l16 * 4) =
                        pack4(ak[nt][0] + bk4.x, ak[nt][1] + bk4.y,
                              ak[nt][2] + bk4.z, ak[nt][3] + bk4.w);
                }
                int ch = p * 16 + l15;
                int r0 = nt * 16 + l16 * 4;
                *(uint2*)(vtw + ch * 72 + r0) =
                    pack4(av[nt][0] + bvs, av[nt][1] + bvs, av[nt][2] + bvs, av[nt][3] + bvs);
            }
        }

        // ---------- preload q/k fragments (pw2 will overwrite qw/kw) --------
        bf16x8 kf[4], qf[4];
        #pragma unroll
        for (int i4 = 0; i4 < 4; ++i4) {
            kf[i4] = *(const bf16x8*)(kw + arow[i4] * 40 + l16 * 8);
            qf[i4] = *(const bf16x8*)(qw + arow[i4] * 40 + l16 * 8);
        }

        // ---------- S^T per q-tile ct: 4 MFMA + in-lane softmax + b64 P -----
        #pragma unroll
        for (int ct = 0; ct < 4; ++ct) {
            f32x4 sT[4];
            __builtin_amdgcn_s_setprio(1);
            #pragma unroll
            for (int mt = 0; mt < 4; ++mt) {
                f32x4 z = (f32x4){0.f,0.f,0.f,0.f};
                sT[mt] = __builtin_amdgcn_mfma_f32_16x16x32_bf16(kf[mt], qf[ct], z, 0, 0, 0);
            }
            __builtin_amdgcn_s_setprio(0);

            float vv[4][4];
            float mx = -1e30f;
            #pragma unroll
            for (int mt = 0; mt < 4; ++mt) {
                float b0 = bf2f((unsigned short)(bmu[ct][mt].x & 0xffff));
                float b1 = bf2f((unsigned short)(bmu[ct][mt].x >> 16));
                float b2 = bf2f((unsigned short)(bmu[ct][mt].y & 0xffff));
                float b3 = bf2f((unsigned short)(bmu[ct][mt].y >> 16));
                float bj[4] = {b0, b1, b2, b3};
                #pragma unroll
                for (int j = 0; j < 4; ++j) {
                    float v = sT[mt][j] + bj[j];
                    if (mt * 16 + l16 * 4 + j >= NTOK) v = -1e30f;  // key mask
                    vv[mt][j] = v;
                    mx = fmaxf(mx, v);
                }
            }
            mx = fmaxf(mx, __shfl_xor(mx, 16));
            mx = fmaxf(mx, __shfl_xor(mx, 32));
            float sum = 0.f;
            #pragma unroll
            for (int mt = 0; mt < 4; ++mt)
                #pragma unroll
                for (int j = 0; j < 4; ++j) {
                    float e = __expf(vv[mt][j] - mx);
                    vv[mt][j] = e;
                    sum += e;
                }
            sum += __shfl_xor(sum, 16);
            sum += __shfl_xor(sum, 32);
            float inv = 1.f / sum;
            int q = ct * 16 + l15;
            if (q < NTOK) {
                #pragma unroll
                for (int mt = 0; mt < 4; ++mt)
                    *(uint2*)(pw2 + q * 72 + mt * 16 + l16 * 4) =
                        pack4(vv[mt][0] * inv, vv[mt][1] * inv,
                              vv[mt][2] * inv, vv[mt][3] * inv);
            }
        }

        // ---------- out^T = v^T @ P^T : 2 ch-tiles x 4 q-tiles, K=64 --------
        f32x4 o_[2][4];
        #pragma unroll
        for (int a = 0; a < 2; ++a)
            #pragma unroll
            for (int ct = 0; ct < 4; ++ct) o_[a][ct] = (f32x4){0.f,0.f,0.f,0.f};
        __builtin_amdgcn_s_setprio(1);
        #pragma unroll
        for (int kt = 0; kt < 2; ++kt) {
            bf16x8 pf[4];
            #pragma unroll
            for (int ct = 0; ct < 4; ++ct)
                pf[ct] = *(const bf16x8*)(pw2 + arow[ct] * 72 + kt * 32 + l16 * 8);
            #pragma unroll
            for (int a = 0; a < 2; ++a) {
                bf16x8 vf = *(const bf16x8*)(vtw + (a * 16 + l15) * 72 + kt * 32 + l16 * 8);
                #pragma unroll
                for (int ct = 0; ct < 4; ++ct)
                    o_[a][ct] = __builtin_amdgcn_mfma_f32_16x16x32_bf16(vf, pf[ct], o_[a][ct], 0, 0, 0);
            }
        }
        __builtin_amdgcn_s_setprio(0);

        #pragma unroll
        for (int a = 0; a < 2; ++a)
            #pragma unroll
            for (int ct = 0; ct < 4; ++ct)
                ob[hh][a][ct] = pack4(o_[a][ct][0], o_[a][ct][1], o_[a][ct][2], o_[a][ct][3]);
    }

    __syncthreads();   // barrier 2: all waves past their last xs read

    // ---- scatter attention output (both heads) into xs as bf16, b64 stores
    #pragma unroll
    for (int hh = 0; hh < 2; ++hh) {
        #pragma unroll
        for (int a = 0; a < 2; ++a) {
            #pragma unroll
            for (int ct = 0; ct < 4; ++ct) {
                int tok = ct * 16 + l15;
                if (tok < NTOK) {
                    int ch0 = (wv + 4 * hh) * HD + a * 16 + l16 * 4;
                    int ad = tok * 256 + ((ch0 & ~7) ^ ((tok & 7) << 3)) + (ch0 & 7);
                    *(uint2*)(xs + ad) = ob[hh][a][ct];
                }
            }
        }
    }
    __syncthreads();   // barrier 3: ao ready in xs

    // ---- proj (swapped): D col=tok -> float4 stores. Wave: 4 col-tiles.
    f32x4 pacc[4][4];   // [ct][u]
    #pragma unroll
    for (int ct = 0; ct < 4; ++ct)
        #pragma unroll
        for (int u = 0; u < 4; ++u) pacc[ct][u] = (f32x4){0.f,0.f,0.f,0.f};

    __builtin_amdgcn_s_setprio(1);
    #pragma unroll
    for (int ks2 = 0; ks2 < 8; ++ks2) {
        bf16x8 xf[4];
        #pragma unroll
        for (int ct = 0; ct < 4; ++ct)
            xf[ct] = *(const bf16x8*)(xs + arow[ct] * 256 +
                       ((ks2 * 32 + l16 * 8) ^ ((arow[ct] & 7) << 3)));
        #pragma unroll
        for (int u = 0; u < 4; ++u) {
            bf16x8 wf = *(const bf16x8*)(wpf + (size_t)((wv * 4 + u) * 8 + ks2) * 512 + lane * 8);
            #pragma unroll
            for (int ct = 0; ct < 4; ++ct)
                pacc[ct][u] = __builtin_amdgcn_mfma_f32_16x16x32_bf16(wf, xf[ct], pacc[ct][u], 0, 0, 0);
        }
    }
    __builtin_amdgcn_s_setprio(0);

    #pragma unroll
    for (int u = 0; u < 4; ++u) {
        int bt = wv * 4 + u;
        int base = (bt >> 3) * 128 + (bt & 7) * 16;
        float4 pb4 = *(const float4*)(pb + base + l16 * 4);
        #pragma unroll
        for (int ct = 0; ct < 4; ++ct) {
            int tok = ct * 16 + l15;
            if (tok < NTOK) {
                float4 r;
                r.x = pacc[ct][u][0] + pb4.x;
                r.y = pacc[ct][u][1] + pb4.y;
                r.z = pacc[ct][u][2] + pb4.z;
                r.w = pacc[ct][u][3] + pb4.w;
                *(float4*)(out + ((size_t)bw * NTOK + tok) * DIM + base + l16 * 4) = r;
            }
        }
    }
}

extern "C" void kernel_launch(void* const* d_in, const int* in_sizes, int n_in,
                              void* d_out, int out_size, void* d_ws, size_t ws_size,
                              hipStream_t stream) {
    const float* x    = (const float*)d_in[0];
    const float* mask = (const float*)d_in[1];
    const float* qkvw = (const float*)d_in[2];
    const float* qkvb = (const float*)d_in[3];
    const float* pw   = (const float*)d_in[4];
    const float* pb   = (const float*)d_in[5];
    const float* bt   = (const float*)d_in[6];
    const int*   ri   = (const int*)d_in[7];
    float* out = (float*)d_out;

    unsigned short* wqf = (unsigned short*)d_ws;
    unsigned short* wpf = wqf + 196608;
    unsigned short* bmf = (unsigned short*)((char*)d_ws + 524288);  // 4 MB

    const int nwin = in_sizes[0] / (NTOK * DIM);      // 4096
    const int total = 262144 + 64 * HEADS * 16 * 256; // 2359296

    k0_prep<<<(total + 255) / 256, 256, 0, stream>>>(qkvw, pw, mask, bt, ri,
                                                     wqf, wpf, bmf, total);
    k1_fused<<<nwin, 256, 0, stream>>>(x, qkvb, pb, wqf, wpf, bmf, out);
}

// Round 9
// 265.747 us; speedup vs baseline: 1.2574x; 1.0104x over previous
//
#include <hip/hip_runtime.h>
#include <hip/hip_bf16.h>

#define NTOK 49
#define DIM 256
#define HEADS 8
#define HD 32
#define SCALE 0.17677669529663687f

typedef float f32x4 __attribute__((ext_vector_type(4)));
typedef short bf16x8 __attribute__((ext_vector_type(8)));
typedef short bf16x4 __attribute__((ext_vector_type(4)));

__device__ __forceinline__ unsigned short f2bf(float f) {
    union { __hip_bfloat16 h; unsigned short u; } c;
    c.h = __float2bfloat16(f);
    return c.u;
}
__device__ __forceinline__ float bf2f(unsigned short u) {
    return __builtin_bit_cast(float, (unsigned)u << 16);
}
__device__ __forceinline__ uint2 pack4(float a, float b, float c, float d) {
    uint2 r;
    r.x = (unsigned)f2bf(a) | ((unsigned)f2bf(b) << 16);
    r.y = (unsigned)f2bf(c) | ((unsigned)f2bf(d) << 16);
    return r;
}

// K=16 bf16 MFMA on packed uint2 fragments (4 bf16/lane, k = (lane>>4)*4+j).
// Its A/B fragment layout coincides with the 16x16x32 D-fragment layout,
// letting qkv outputs feed S^T / PV directly from registers.
__device__ __forceinline__ f32x4 mfma16(uint2 a, uint2 b, f32x4 c) {
    bf16x4 av = __builtin_bit_cast(bf16x4, a);
    bf16x4 bv = __builtin_bit_cast(bf16x4, b);
#if __has_builtin(__builtin_amdgcn_mfma_f32_16x16x16bf16_1k)
    return __builtin_amdgcn_mfma_f32_16x16x16bf16_1k(av, bv, c, 0, 0, 0);
#elif __has_builtin(__builtin_amdgcn_mfma_f32_16x16x16_bf16)
    return __builtin_amdgcn_mfma_f32_16x16x16_bf16(av, bv, c, 0, 0, 0);
#else
    f32x4 d;
    asm volatile("v_mfma_f32_16x16x16_bf16 %0, %1, %2, %3"
                 : "=v"(d) : "v"(av), "v"(bv), "v"(c));
    return d;
#endif
}

// ---------------------------------------------------------------------------
// K0: one-time prep into d_ws (byte-identical to round 8):
//   wqf [196608] bf16 : qkv_w in MFMA fragment order
//   wpf [65536]  bf16 : proj_w in MFMA fragment order
//   bmf [2097152] bf16 : mask+bias in S^T D-fragment order
//       idx = ((ws*8+h)*16 + ct*4 + mt)*256 + lane*4 + j
//       -> (query q = ct*16 + (lane&15), key = mt*16 + (lane>>4)*4 + j)
// ---------------------------------------------------------------------------
__global__ void k0_prep(const float* __restrict__ qkv_w, const float* __restrict__ proj_w,
                        const float* __restrict__ mask, const float* __restrict__ bias_table,
                        const int* __restrict__ rel_idx,
                        unsigned short* __restrict__ wqf, unsigned short* __restrict__ wpf,
                        unsigned short* __restrict__ bmf, int total)
{
    int i = blockIdx.x * 256 + threadIdx.x;
    if (i >= total) return;
    if (i < 196608) {
        int j = i & 7, q = i >> 3;
        int lane = q & 63; q >>= 6;
        int ks2 = q & 7;  q >>= 3;
        int tt = q % 6;   q /= 6;
        int h  = q;
        int n96 = tt * 16 + (lane & 15);
        int seg = n96 >> 5, ch = n96 & 31;
        wqf[i] = f2bf(qkv_w[(seg * 256 + h * HD + ch) * 256 + ks2 * 32 + (lane >> 4) * 8 + j]);
    } else if (i < 262144) {
        int u = i - 196608;
        int j = u & 7, q = u >> 3;
        int lane = q & 63; q >>= 6;
        int ks2 = q & 7;  q >>= 3;
        int bt = q;                       // 0..15
        int n = (bt >> 3) * 128 + (bt & 7) * 16 + (lane & 15);
        wpf[u] = f2bf(proj_w[n * 256 + ks2 * 32 + (lane >> 4) * 8 + j]);
    } else {
        int u = i - 262144;               // [0, 2097152)
        int j = u & 3;
        int lane = (u >> 2) & 63;
        int g = u >> 8;                   // ws*128 + h*16 + ct*4 + mt
        int mt = g & 3, ct = (g >> 2) & 3, h = (g >> 4) & 7, ws = g >> 7;
        int q = ct * 16 + (lane & 15);
        int key = mt * 16 + ((lane >> 4) & 3) * 4 + j;
        float v = 0.f;
        if (q < NTOK && key < NTOK)
            v = mask[ws * 2401 + q * NTOK + key] + bias_table[rel_idx[q * NTOK + key] * HEADS + h];
        bmf[u] = f2bf(v);
    }
}

// ---------------------------------------------------------------------------
// K1: fully fused qkv + attention + proj. 4096 blocks x 256 threads (4 waves).
// Wave wv owns heads {wv, wv+4}. Attention is fully REGISTER-resident:
// q/k/v/P never touch LDS (16x16x16 MFMAs consume the 16x16x32 D-frags
// directly). LDS = xs only (25088 B) -> occupancy is register-bound;
// __launch_bounds__(256,3) targets 3 waves/EU (VGPR cap 170, 3 blocks/CU).
// 3 barriers per block.
// ---------------------------------------------------------------------------
__global__ __launch_bounds__(256, 3)
void k1_fused(
    const float* __restrict__ x,             // [4096,49,256] f32
    const float* __restrict__ qkv_b,         // [768] f32
    const float* __restrict__ pb,            // [256] f32
    const unsigned short* __restrict__ wqf,  // fragment-ordered qkv_w bf16
    const unsigned short* __restrict__ wpf,  // fragment-ordered proj_w bf16
    const unsigned short* __restrict__ bmf,  // fragment-ordered mask+bias bf16
    float* __restrict__ out)                 // [4096,49,256] f32 final
{
    __shared__ unsigned short xs[49 * 256];  // 25088 B (x; reused for ao)

    const int t = threadIdx.x, bw = blockIdx.x;
    const int lane = t & 63, wv = t >> 6;
    const int l15 = lane & 15, l16 = lane >> 4;

    // ---- stage x rows 0..48 -> bf16 LDS (XOR swizzle on 16B chunks)
    const float* xw = x + (size_t)bw * NTOK * DIM;
    for (int cidx = t; cidx < NTOK * 32; cidx += 256) {
        int row = cidx >> 5, c8 = cidx & 31;
        float4 a = *(const float4*)(xw + row * DIM + c8 * 8);
        float4 b = *(const float4*)(xw + row * DIM + c8 * 8 + 4);
        bf16x8 v;
        v[0] = (short)f2bf(a.x); v[1] = (short)f2bf(a.y);
        v[2] = (short)f2bf(a.z); v[3] = (short)f2bf(a.w);
        v[4] = (short)f2bf(b.x); v[5] = (short)f2bf(b.y);
        v[6] = (short)f2bf(b.z); v[7] = (short)f2bf(b.w);
        *(bf16x8*)(xs + row * 256 + ((c8 * 8) ^ ((row & 7) << 3))) = v;
    }
    __syncthreads();   // barrier 1: xs ready

    int arow[4];
    #pragma unroll
    for (int i4 = 0; i4 < 4; ++i4) {
        int r = i4 * 16 + l15;
        arow[i4] = r > 48 ? 48 : r;     // row clamp (49 real rows in xs)
    }

    uint2 ob[2][2][4];                  // packed bf16 out^T frags [hh][a][ct]

    #pragma unroll
    for (int hh = 0; hh < 2; ++hh) {
        const int h = wv + 4 * hh;
        const unsigned short* wb = wqf + (size_t)h * 24576;
        uint2 qpk[4][2], kpk[4][2], vpk[4][2];   // [tok-tile][ch-chunk p]
        uint2 bmu[4][4];                         // [ct][mt] bias+mask frags

        // ---------- qkv: 2 passes of 16x16x32; outputs stay in registers ----
        #pragma unroll
        for (int p = 0; p < 2; ++p) {
            f32x4 aq[4], ak[4], av[4];
            #pragma unroll
            for (int nt = 0; nt < 4; ++nt) {
                aq[nt] = (f32x4){0.f,0.f,0.f,0.f};
                ak[nt] = (f32x4){0.f,0.f,0.f,0.f};
                av[nt] = (f32x4){0.f,0.f,0.f,0.f};
            }
            __builtin_amdgcn_s_setprio(1);
            #pragma unroll
            for (int ks2 = 0; ks2 < 8; ++ks2) {
                bf16x8 xf[4];
                #pragma unroll
                for (int nt = 0; nt < 4; ++nt)
                    xf[nt] = *(const bf16x8*)(xs + arow[nt] * 256 +
                               ((ks2 * 32 + l16 * 8) ^ ((arow[nt] & 7) << 3)));
                bf16x8 wqf_ = *(const bf16x8*)(wb + ((p    ) * 8 + ks2) * 512 + lane * 8);
                bf16x8 wkf_ = *(const bf16x8*)(wb + ((2 + p) * 8 + ks2) * 512 + lane * 8);
                bf16x8 wvf_ = *(const bf16x8*)(wb + ((4 + p) * 8 + ks2) * 512 + lane * 8);
                #pragma unroll
                for (int nt = 0; nt < 4; ++nt) {
                    aq[nt] = __builtin_amdgcn_mfma_f32_16x16x32_bf16(wqf_, xf[nt], aq[nt], 0, 0, 0);
                    ak[nt] = __builtin_amdgcn_mfma_f32_16x16x32_bf16(wkf_, xf[nt], ak[nt], 0, 0, 0);
                    av[nt] = __builtin_amdgcn_mfma_f32_16x16x32_bf16(xf[nt], wvf_, av[nt], 0, 0, 0);
                }
            }
            __builtin_amdgcn_s_setprio(0);

            if (p == 1) {   // prefetch softmax bias+mask (hidden by epilogue)
                #pragma unroll
                for (int ct = 0; ct < 4; ++ct)
                    #pragma unroll
                    for (int mt = 0; mt < 4; ++mt)
                        bmu[ct][mt] = *(const uint2*)(bmf +
                            (((size_t)(((bw & 63) * 8 + h) * 16 + ct * 4 + mt)) << 8) + (lane << 2));
            }

            // epilogue: bias + pack into MFMA-K16-ready register fragments
            float4 bq4 = *(const float4*)(qkv_b + h * HD + p * 16 + l16 * 4);
            float4 bk4 = *(const float4*)(qkv_b + 256 + h * HD + p * 16 + l16 * 4);
            float  bvs = qkv_b[512 + h * HD + p * 16 + l15];
            #pragma unroll
            for (int nt = 0; nt < 4; ++nt) {
                qpk[nt][p] = pack4((aq[nt][0] + bq4.x) * SCALE, (aq[nt][1] + bq4.y) * SCALE,
                                   (aq[nt][2] + bq4.z) * SCALE, (aq[nt][3] + bq4.w) * SCALE);
                kpk[nt][p] = pack4(ak[nt][0] + bk4.x, ak[nt][1] + bk4.y,
                                   ak[nt][2] + bk4.z, ak[nt][3] + bk4.w);
                vpk[nt][p] = pack4(av[nt][0] + bvs, av[nt][1] + bvs,
                                   av[nt][2] + bvs, av[nt][3] + bvs);
            }
        }

        // ---------- per q-tile ct: S^T (reg) + softmax + PV (reg) ----------
        #pragma unroll
        for (int ct = 0; ct < 4; ++ct) {
            f32x4 sT[4];
            __builtin_amdgcn_s_setprio(1);
            #pragma unroll
            for (int mt = 0; mt < 4; ++mt) {
                f32x4 z = (f32x4){0.f,0.f,0.f,0.f};
                sT[mt] = mfma16(kpk[mt][1], qpk[ct][1],
                                mfma16(kpk[mt][0], qpk[ct][0], z));
            }
            __builtin_amdgcn_s_setprio(0);

            float vv[4][4];
            float mx = -1e30f;
            #pragma unroll
            for (int mt = 0; mt < 4; ++mt) {
                float b0 = bf2f((unsigned short)(bmu[ct][mt].x & 0xffff));
                float b1 = bf2f((unsigned short)(bmu[ct][mt].x >> 16));
                float b2 = bf2f((unsigned short)(bmu[ct][mt].y & 0xffff));
                float b3 = bf2f((unsigned short)(bmu[ct][mt].y >> 16));
                float bj[4] = {b0, b1, b2, b3};
                #pragma unroll
                for (int j = 0; j < 4; ++j) {
                    float v = sT[mt][j] + bj[j];
                    if (mt * 16 + l16 * 4 + j >= NTOK) v = -1e30f;  // key mask
                    vv[mt][j] = v;
                    mx = fmaxf(mx, v);
                }
            }
            mx = fmaxf(mx, __shfl_xor(mx, 16));
            mx = fmaxf(mx, __shfl_xor(mx, 32));
            float sum = 0.f;
            #pragma unroll
            for (int mt = 0; mt < 4; ++mt)
                #pragma unroll
                for (int j = 0; j < 4; ++j) {
                    float e = __expf(vv[mt][j] - mx);
                    vv[mt][j] = e;
                    sum += e;
                }
            sum += __shfl_xor(sum, 16);
            sum += __shfl_xor(sum, 32);
            float inv = 1.f / sum;

            uint2 ppk[4];
            #pragma unroll
            for (int mt = 0; mt < 4; ++mt)
                ppk[mt] = pack4(vv[mt][0] * inv, vv[mt][1] * inv,
                                vv[mt][2] * inv, vv[mt][3] * inv);

            f32x4 o0 = (f32x4){0.f,0.f,0.f,0.f};
            f32x4 o1 = (f32x4){0.f,0.f,0.f,0.f};
            __builtin_amdgcn_s_setprio(1);
            #pragma unroll
            for (int mt = 0; mt < 4; ++mt) {
                o0 = mfma16(vpk[mt][0], ppk[mt], o0);
                o1 = mfma16(vpk[mt][1], ppk[mt], o1);
            }
            __builtin_amdgcn_s_setprio(0);
            ob[hh][0][ct] = pack4(o0[0], o0[1], o0[2], o0[3]);
            ob[hh][1][ct] = pack4(o1[0], o1[1], o1[2], o1[3]);
        }
    }

    __syncthreads();   // barrier 2: all waves past their last xs read

    // ---- scatter attention output (both heads) into xs as bf16, b64 stores
    #pragma unroll
    for (int hh = 0; hh < 2; ++hh) {
        #pragma unroll
        for (int a = 0; a < 2; ++a) {
            #pragma unroll
            for (int ct = 0; ct < 4; ++ct) {
                int tok = ct * 16 + l15;
                if (tok < NTOK) {
                    int ch0 = (wv + 4 * hh) * HD + a * 16 + l16 * 4;
                    int ad = tok * 256 + ((ch0 & ~7) ^ ((tok & 7) << 3)) + (ch0 & 7);
                    *(uint2*)(xs + ad) = ob[hh][a][ct];
                }
            }
        }
    }
    __syncthreads();   // barrier 3: ao ready in xs

    // ---- proj (swapped): D col=tok -> float4 stores. Wave: 4 col-tiles.
    f32x4 pacc[4][4];   // [ct][u]
    #pragma unroll
    for (int ct = 0; ct < 4; ++ct)
        #pragma unroll
        for (int u = 0; u < 4; ++u) pacc[ct][u] = (f32x4){0.f,0.f,0.f,0.f};

    __builtin_amdgcn_s_setprio(1);
    #pragma unroll
    for (int ks2 = 0; ks2 < 8; ++ks2) {
        bf16x8 xf[4];
        #pragma unroll
        for (int ct = 0; ct < 4; ++ct)
            xf[ct] = *(const bf16x8*)(xs + arow[ct] * 256 +
                       ((ks2 * 32 + l16 * 8) ^ ((arow[ct] & 7) << 3)));
        #pragma unroll
        for (int u = 0; u < 4; ++u) {
            bf16x8 wf = *(const bf16x8*)(wpf + (size_t)((wv * 4 + u) * 8 + ks2) * 512 + lane * 8);
            #pragma unroll
            for (int ct = 0; ct < 4; ++ct)
                pacc[ct][u] = __builtin_amdgcn_mfma_f32_16x16x32_bf16(wf, xf[ct], pacc[ct][u], 0, 0, 0);
        }
    }
    __builtin_amdgcn_s_setprio(0);

    #pragma unroll
    for (int u = 0; u < 4; ++u) {
        int bt = wv * 4 + u;
        int base = (bt >> 3) * 128 + (bt & 7) * 16;
        float4 pb4 = *(const float4*)(pb + base + l16 * 4);
        #pragma unroll
        for (int ct = 0; ct < 4; ++ct) {
            int tok = ct * 16 + l15;
            if (tok < NTOK) {
                float4 r;
                r.x = pacc[ct][u][0] + pb4.x;
                r.y = pacc[ct][u][1] + pb4.y;
                r.z = pacc[ct][u][2] + pb4.z;
                r.w = pacc[ct][u][3] + pb4.w;
                *(float4*)(out + ((size_t)bw * NTOK + tok) * DIM + base + l16 * 4) = r;
            }
        }
    }
}

extern "C" void kernel_launch(void* const* d_in, const int* in_sizes, int n_in,
                              void* d_out, int out_size, void* d_ws, size_t ws_size,
                              hipStream_t stream) {
    const float* x    = (const float*)d_in[0];
    const float* mask = (const float*)d_in[1];
    const float* qkvw = (const float*)d_in[2];
    const float* qkvb = (const float*)d_in[3];
    const float* pw   = (const float*)d_in[4];
    const float* pb   = (const float*)d_in[5];
    const float* bt   = (const float*)d_in[6];
    const int*   ri   = (const int*)d_in[7];
    float* out = (float*)d_out;

    unsigned short* wqf = (unsigned short*)d_ws;
    unsigned short* wpf = wqf + 196608;
    unsigned short* bmf = (unsigned short*)((char*)d_ws + 524288);  // 4 MB

    const int nwin = in_sizes[0] / (NTOK * DIM);      // 4096
    const int total = 262144 + 64 * HEADS * 16 * 256; // 2359296

    k0_prep<<<(total + 255) / 256, 256, 0, stream>>>(qkvw, pw, mask, bt, ri,
                                                     wqf, wpf, bmf, total);
    k1_fused<<<nwin, 256, 0, stream>>>(x, qkvb, pb, wqf, wpf, bmf, out);
}